// Round 10
// baseline (643.539 us; speedup 1.0000x reference)
//
#include <hip/hip_runtime.h>
#include <math.h>

#define NP 4
#define NN 8192
#define NM 8192

// ws layout (float units):
//   AKV: neg-cad-t f16 k-vectors, 2 x half8/point: 4*8192 pts  -> 262144 floats
//   BKV: cam f16 k-vectors, 2 x half8/point                    -> 262144
//   HA:  0.5|cad_t|^2 f32 per point                            -> 32768
//   HB:  0.5|cam|^2 f32 per point                              -> 32768
//   MINS: minA[32768] then minB[32768] (0.5*d^2 values)        -> 65536
//   ZP:  16B zero page for MFMA k16..31 operand halves
#define AKV_OFF 0
#define BKV_OFF 262144
#define HA_OFF  524288
#define HB_OFF  557056
#define MINS_OFF 589824
#define ZP_OFF  655360
// total ws use: 655368 floats = 2.63 MB

typedef _Float16 half8 __attribute__((ext_vector_type(8)));
typedef float float4v __attribute__((ext_vector_type(4)));

__device__ inline void split16(float v, _Float16& h, _Float16& l) {
    h = (_Float16)v;
    l = (_Float16)(v - (float)h);
}

__device__ inline void make_transform(const float* __restrict__ quat,
                                      const float* __restrict__ tra,
                                      int p, float T[12]) {
    float q0 = quat[p * 4 + 0], q1 = quat[p * 4 + 1];
    float q2 = quat[p * 4 + 2], q3 = quat[p * 4 + 3];
    float inv = 1.0f / sqrtf(q0 * q0 + q1 * q1 + q2 * q2 + q3 * q3);
    float a = q0 * inv, b = q1 * inv, c = q2 * inv, d = q3 * inv;
    T[0] = 1.0f - 2.0f * c * c - 2.0f * d * d;
    T[1] = 2.0f * b * c - 2.0f * a * d;
    T[2] = 2.0f * a * c + 2.0f * b * d;
    T[3] = tra[p * 3 + 0];
    T[4] = 2.0f * b * c + 2.0f * a * d;
    T[5] = 1.0f - 2.0f * b * b - 2.0f * d * d;
    T[6] = 2.0f * c * d - 2.0f * a * b;
    T[7] = tra[p * 3 + 1];
    T[8] = 2.0f * b * d - 2.0f * a * c;
    T[9] = 2.0f * a * b + 2.0f * c * d;
    T[10] = 1.0f - 2.0f * b * b - 2.0f * c * c;
    T[11] = tra[p * 3 + 2];
}

// 256 blocks x 256 threads over 65536 points.
// cad (idx<32768): transform, NEGATE, f16 hi/lo split, A-layout k-vec:
//   k0..8 = [nh0 nh1 nh2 nl0 nl1 nl2 nh0 nh1 nh2], rest 0.
// cam: B-layout k-vec: k0..8 = [h0 h1 h2 h0 h1 h2 l0 l1 l2].
// Sum over k of A_k*B_k = -(h.h + l.h + h.l) = -S with |err| ~ |l||l| ~ 1e-7.
__global__ __launch_bounds__(256) void prep_kernel(
    const float* __restrict__ cam, const float* __restrict__ cad,
    const float* __restrict__ quat, const float* __restrict__ tra,
    float* __restrict__ ws, float* __restrict__ out) {
    int idx = blockIdx.x * 256 + threadIdx.x;  // [0, 65536)
    const float INF = __uint_as_float(0x7f800000u);

    if (idx < NP * NM) {
        int p = idx >> 13;
        float T[12];
        make_transform(quat, tra, p, T);
        float x = cad[idx * 3 + 0];
        float y = cad[idx * 3 + 1];
        float z = cad[idx * 3 + 2];
        float vx = fmaf(T[0], x, fmaf(T[1], y, fmaf(T[2], z, T[3])));
        float vy = fmaf(T[4], x, fmaf(T[5], y, fmaf(T[6], z, T[7])));
        float vz = fmaf(T[8], x, fmaf(T[9], y, fmaf(T[10], z, T[11])));
        ws[HA_OFF + idx] = 0.5f * (vx * vx + vy * vy + vz * vz);
        _Float16 hx, lx, hy, ly, hz, lz;
        split16(-vx, hx, lx);
        split16(-vy, hy, ly);
        split16(-vz, hz, lz);
        half8 k0 = {hx, hy, hz, lx, ly, lz, hx, hy};
        half8 k1 = {hz, (_Float16)0, (_Float16)0, (_Float16)0,
                    (_Float16)0, (_Float16)0, (_Float16)0, (_Float16)0};
        ((half8*)(ws + AKV_OFF))[idx * 2 + 0] = k0;
        ((half8*)(ws + AKV_OFF))[idx * 2 + 1] = k1;
    } else {
        int k = idx - NP * NM;
        float vx = cam[k * 3 + 0];
        float vy = cam[k * 3 + 1];
        float vz = cam[k * 3 + 2];
        ws[HB_OFF + k] = 0.5f * (vx * vx + vy * vy + vz * vz);
        _Float16 hx, lx, hy, ly, hz, lz;
        split16(vx, hx, lx);
        split16(vy, hy, ly);
        split16(vz, hz, lz);
        half8 k0 = {hx, hy, hz, hx, hy, hz, lx, ly};
        half8 k1 = {lz, (_Float16)0, (_Float16)0, (_Float16)0,
                    (_Float16)0, (_Float16)0, (_Float16)0, (_Float16)0};
        ((half8*)(ws + BKV_OFF))[k * 2 + 0] = k0;
        ((half8*)(ws + BKV_OFF))[k * 2 + 1] = k1;
    }
    ws[MINS_OFF + idx] = INF;
    if (idx < 8) ws[ZP_OFF + idx] = 0.0f;

    if (idx < 64) {
        int p2 = idx >> 4;
        int r = (idx >> 2) & 3;
        int c = idx & 3;
        float T[12];
        make_transform(quat, tra, p2, T);
        float v;
        if (r == 3)
            v = (c == 3) ? 1.0f : 0.0f;
        else
            v = T[r * 4 + c];
        out[1 + idx] = v;
    } else if (idx == 64) {
        out[0] = 0.0f;
    }
}

// grid (64, 32, 4) x 64 threads (1 wave). Wave strip: 128 m x 256 n.
// Per 16x16 tile: C preload = ha[row]+hb[col]; D = C + (-A)*B = 0.5*d^2
// directly (mfma_f32_16x16x32_f16, layouts: A[m=lane&15][k=quad*8+j],
// B[n=lane&15][k=quad*8+j], C/D col=lane&15 row=quad*4+reg).
// One pass serves BOTH chamfer directions: row-min -> minA, col-min -> minB.
__global__ __launch_bounds__(64)
__attribute__((amdgpu_waves_per_eu(2, 3)))
void chamfer_mfma(const float* __restrict__ ws, float* __restrict__ mins) {
    int lane = threadIdx.x;
    int quad = lane >> 4;
    int col = lane & 15;
    int p8 = blockIdx.z * 8192;
    int mb = blockIdx.x * 128;
    int nb = blockIdx.y * 256;
    const float INF = __uint_as_float(0x7f800000u);

    const half8* akv = (const half8*)(ws + AKV_OFF);
    const half8* bkv = (const half8*)(ws + BKV_OFF);
    const half8* zpp = (const half8*)(ws + ZP_OFF);
    const float* hap = ws + HA_OFF + p8;
    const float* hbp = ws + HB_OFF + p8;

    // Per-strip A-side state: 8 m-tiles of 16 rows.
    half8 af[8];
    float4v haT[8];
    float4v minA[8];
#pragma unroll
    for (int i = 0; i < 8; ++i) {
        int m = mb + i * 16 + col;
        const half8* ap = (quad < 2) ? (akv + (size_t)(p8 + m) * 2 + quad) : zpp;
        af[i] = *ap;
        haT[i] = *(const float4v*)(hap + mb + i * 16 + quad * 4);
        minA[i] = {INF, INF, INF, INF};
    }
    float mB[16];
#pragma unroll
    for (int j = 0; j < 16; ++j) mB[j] = INF;

#pragma unroll
    for (int j = 0; j < 16; ++j) {
        int n = nb + j * 16 + col;
        const half8* bp = (quad < 2) ? (bkv + (size_t)(p8 + n) * 2 + quad) : zpp;
        half8 bf = *bp;
        float hbs = hbp[nb + j * 16 + col];
#pragma unroll
        for (int i = 0; i < 8; ++i) {
            float4v c = haT[i] + hbs;  // ha[row]+hb[col] preloaded into C
            c = __builtin_amdgcn_mfma_f32_16x16x32_f16(af[i], bf, c, 0, 0, 0);
            minA[i].x = fminf(minA[i].x, c.x);
            minA[i].y = fminf(minA[i].y, c.y);
            minA[i].z = fminf(minA[i].z, c.z);
            minA[i].w = fminf(minA[i].w, c.w);
            float cand = fminf(fminf(c.x, c.y), fminf(c.z, c.w));
            mB[j] = fminf(mB[j], cand);
        }
    }

    // minA: reduce across cols (lanes 0..15 of each quad), rows = quad*4+r.
#pragma unroll
    for (int i = 0; i < 8; ++i) {
#pragma unroll
        for (int r = 0; r < 4; ++r) {
            float v = minA[i][r];
            v = fminf(v, __shfl_xor(v, 1));
            v = fminf(v, __shfl_xor(v, 2));
            v = fminf(v, __shfl_xor(v, 4));
            v = fminf(v, __shfl_xor(v, 8));
            if (col == 0)
                atomicMin((unsigned int*)&mins[p8 + mb + i * 16 + quad * 4 + r],
                          __float_as_uint(v));
        }
    }
    // minB: reduce across quads (rows), col fixed.
#pragma unroll
    for (int j = 0; j < 16; ++j) {
        float v = mB[j];
        v = fminf(v, __shfl_xor(v, 16));
        v = fminf(v, __shfl_xor(v, 32));
        if (lane < 16)
            atomicMin((unsigned int*)&mins[NP * NM + p8 + nb + j * 16 + lane],
                      __float_as_uint(v));
    }
}

__global__ __launch_bounds__(256) void finalize_kernel(
    const float* __restrict__ ws, const float* __restrict__ w,
    float* __restrict__ out) {
    // mins hold s = 0.5*d^2 -> d = sqrt(max(2s, 0)).
    const float* vals = ws + MINS_OFF;
    int i = blockIdx.x * 256 + threadIdx.x;  // [0, 32768)
    int tid = threadIdx.x;

    float wl[4] = {w[0], w[1], w[2], w[3]};

    int i2 = i + 32768;
    float acc = wl[(i >> 13) & 3] * sqrtf(fmaxf(2.0f * vals[i], 0.0f)) +
                wl[(i2 >> 13) & 3] * sqrtf(fmaxf(2.0f * vals[i2], 0.0f));

#pragma unroll
    for (int off = 32; off > 0; off >>= 1) acc += __shfl_down(acc, off, 64);

    __shared__ float wsum[4];
    if ((tid & 63) == 0) wsum[tid >> 6] = acc;
    __syncthreads();
    if (tid == 0) {
        float blocksum = (wsum[0] + wsum[1] + wsum[2] + wsum[3]) * (1.0f / 8192.0f);
        atomicAdd(out, blocksum);
    }
}

extern "C" void kernel_launch(void* const* d_in, const int* in_sizes, int n_in,
                              void* d_out, int out_size, void* d_ws, size_t ws_size,
                              hipStream_t stream) {
    const float* cam = (const float*)d_in[0];   // (P, N, 3)
    const float* cad = (const float*)d_in[1];   // (P, M, 3)
    const float* w = (const float*)d_in[2];     // (P,)
    const float* quat = (const float*)d_in[3];  // (P, 4)
    const float* tra = (const float*)d_in[4];   // (P, 3, 1)
    float* out = (float*)d_out;
    float* ws = (float*)d_ws;

    prep_kernel<<<256, 256, 0, stream>>>(cam, cad, quat, tra, ws, out);

    dim3 grid(NM / 128, NN / 256, NP);
    chamfer_mfma<<<grid, 64, 0, stream>>>(ws, ws + MINS_OFF);

    finalize_kernel<<<128, 256, 0, stream>>>(ws, w, out);
}

// Round 11
// 124.765 us; speedup vs baseline: 5.1580x; 5.1580x over previous
//
#include <hip/hip_runtime.h>
#include <math.h>

#define NP 4
#define NN 8192
#define NM 8192

// ws layout (float units):
//   AKV: neg-cad-t f16 k-vectors, 2 x half8/point (k0..7, k8..15) -> 262144
//   BKV: cam f16 k-vectors, 2 x half8/point                      -> 262144
//   HA:  0.5|cad_t|^2 f32 per point                              -> 32768
//   HB:  0.5|cam|^2 f32 per point                                -> 32768
//   MINS: minA[32768] then minB[32768] (0.5*d^2 values)          -> 65536
#define AKV_OFF 0
#define BKV_OFF 262144
#define HA_OFF  524288
#define HB_OFF  557056
#define MINS_OFF 589824
// total ws use: 655360 floats = 2.62 MB

typedef _Float16 half8 __attribute__((ext_vector_type(8)));
typedef float float4v __attribute__((ext_vector_type(4)));

__device__ inline void split16(float v, _Float16& h, _Float16& l) {
    h = (_Float16)v;
    l = (_Float16)(v - (float)h);
}

__device__ inline void make_transform(const float* __restrict__ quat,
                                      const float* __restrict__ tra,
                                      int p, float T[12]) {
    float q0 = quat[p * 4 + 0], q1 = quat[p * 4 + 1];
    float q2 = quat[p * 4 + 2], q3 = quat[p * 4 + 3];
    float inv = 1.0f / sqrtf(q0 * q0 + q1 * q1 + q2 * q2 + q3 * q3);
    float a = q0 * inv, b = q1 * inv, c = q2 * inv, d = q3 * inv;
    T[0] = 1.0f - 2.0f * c * c - 2.0f * d * d;
    T[1] = 2.0f * b * c - 2.0f * a * d;
    T[2] = 2.0f * a * c + 2.0f * b * d;
    T[3] = tra[p * 3 + 0];
    T[4] = 2.0f * b * c + 2.0f * a * d;
    T[5] = 1.0f - 2.0f * b * b - 2.0f * d * d;
    T[6] = 2.0f * c * d - 2.0f * a * b;
    T[7] = tra[p * 3 + 1];
    T[8] = 2.0f * b * d - 2.0f * a * c;
    T[9] = 2.0f * a * b + 2.0f * c * d;
    T[10] = 1.0f - 2.0f * b * b - 2.0f * c * c;
    T[11] = tra[p * 3 + 2];
}

// 256 blocks x 256 threads over 65536 points.
// cad (idx<32768): transform, NEGATE, f16 hi/lo split, A-layout k-vec:
//   k0..8 = [nh0 nh1 nh2 nl0 nl1 nl2 nh0 nh1 nh2], rest 0.
// cam: B-layout k-vec: k0..8 = [h0 h1 h2 h0 h1 h2 l0 l1 l2].
// Sum_k A_k*B_k = -(h.h + l.h + h.l) = -S, |err| ~ |l|^2 ~ 1e-7.
// (Layouts verified on HW: R10 passed with absmax 0.0.)
__global__ __launch_bounds__(256) void prep_kernel(
    const float* __restrict__ cam, const float* __restrict__ cad,
    const float* __restrict__ quat, const float* __restrict__ tra,
    float* __restrict__ ws, float* __restrict__ out) {
    int idx = blockIdx.x * 256 + threadIdx.x;  // [0, 65536)
    const float INF = __uint_as_float(0x7f800000u);

    if (idx < NP * NM) {
        int p = idx >> 13;
        float T[12];
        make_transform(quat, tra, p, T);
        float x = cad[idx * 3 + 0];
        float y = cad[idx * 3 + 1];
        float z = cad[idx * 3 + 2];
        float vx = fmaf(T[0], x, fmaf(T[1], y, fmaf(T[2], z, T[3])));
        float vy = fmaf(T[4], x, fmaf(T[5], y, fmaf(T[6], z, T[7])));
        float vz = fmaf(T[8], x, fmaf(T[9], y, fmaf(T[10], z, T[11])));
        ws[HA_OFF + idx] = 0.5f * (vx * vx + vy * vy + vz * vz);
        _Float16 hx, lx, hy, ly, hz, lz;
        split16(-vx, hx, lx);
        split16(-vy, hy, ly);
        split16(-vz, hz, lz);
        half8 k0 = {hx, hy, hz, lx, ly, lz, hx, hy};
        half8 k1 = {hz, (_Float16)0, (_Float16)0, (_Float16)0,
                    (_Float16)0, (_Float16)0, (_Float16)0, (_Float16)0};
        ((half8*)(ws + AKV_OFF))[idx * 2 + 0] = k0;
        ((half8*)(ws + AKV_OFF))[idx * 2 + 1] = k1;
    } else {
        int k = idx - NP * NM;
        float vx = cam[k * 3 + 0];
        float vy = cam[k * 3 + 1];
        float vz = cam[k * 3 + 2];
        ws[HB_OFF + k] = 0.5f * (vx * vx + vy * vy + vz * vz);
        _Float16 hx, lx, hy, ly, hz, lz;
        split16(vx, hx, lx);
        split16(vy, hy, ly);
        split16(vz, hz, lz);
        half8 k0 = {hx, hy, hz, hx, hy, hz, lx, ly};
        half8 k1 = {lz, (_Float16)0, (_Float16)0, (_Float16)0,
                    (_Float16)0, (_Float16)0, (_Float16)0, (_Float16)0};
        ((half8*)(ws + BKV_OFF))[k * 2 + 0] = k0;
        ((half8*)(ws + BKV_OFF))[k * 2 + 1] = k1;
    }
    ws[MINS_OFF + idx] = INF;

    if (idx < 64) {
        int p2 = idx >> 4;
        int r = (idx >> 2) & 3;
        int c = idx & 3;
        float T[12];
        make_transform(quat, tra, p2, T);
        float v;
        if (r == 3)
            v = (c == 3) ? 1.0f : 0.0f;
        else
            v = T[r * 4 + c];
        out[1 + idx] = v;
    } else if (idx == 64) {
        out[0] = 0.0f;
    }
}

// grid (32, 16, 4) x 256 threads (4 waves). Block tile: 256 m x 512 n.
// Wave w owns m-rows [mb+w*64, +64) = 4 i-tiles x all 32 j-tiles.
// Fragment loads go straight to global, CONTIGUOUS per wave: lanes 0-31
// cover a dense 512B region (quad0=k0-half, quad1=k1-half interleaved);
// quads 2,3 hold zeros (A's k16..31 are zero, so B there is don't-care).
// All data (2.6 MB) fits each XCD's L2 -> loads are L1/L2 hits.
// Mins: per-wave shuffle reduce -> LDS partials -> block reduce ->
// COALESCED atomicMin (R10's 1.45 GB fabric storm was uncoalesced atomics).
__global__ __launch_bounds__(256)
__attribute__((amdgpu_waves_per_eu(4, 8)))
void chamfer_mfma(const float* __restrict__ ws, float* mins) {
    int tid = threadIdx.x;
    int lane = tid & 63;
    int w = tid >> 6;
    int quad = lane >> 4;
    int col = lane & 15;
    int p8 = blockIdx.z * 8192;
    int mb = blockIdx.x * 256;
    int nb = blockIdx.y * 512;
    const float INF = __uint_as_float(0x7f800000u);

    const half8* akv = (const half8*)(ws + AKV_OFF);
    const half8* bkv = (const half8*)(ws + BKV_OFF);
    const float* hap = ws + HA_OFF + p8;
    const float* hbp = ws + HB_OFF + p8;

    __shared__ float sMA[256];
    __shared__ float sMB[4 * 512];

    const half8 zf = {(_Float16)0, (_Float16)0, (_Float16)0, (_Float16)0,
                      (_Float16)0, (_Float16)0, (_Float16)0, (_Float16)0};

    int mw = mb + w * 64;
    half8 af[4];
    float4v haT[4];
    float4v minA[4];
#pragma unroll
    for (int i = 0; i < 4; ++i) {
        int m = mw + i * 16 + col;
        af[i] = (quad < 2) ? akv[(size_t)(p8 + m) * 2 + quad] : zf;
        haT[i] = *(const float4v*)(hap + mw + i * 16 + quad * 4);
        minA[i] = {INF, INF, INF, INF};
    }

    // Manual double-buffer on the B fragment (global -> reg prefetch).
    int n0 = nb + col;
    half8 bf = (quad < 2) ? bkv[(size_t)(p8 + n0) * 2 + quad] : zf;
    float hbs = hbp[n0];

#pragma unroll 4
    for (int j = 0; j < 32; ++j) {
        int jn = (j + 1) & 31;  // last iter harmlessly reloads tile 0
        int n = nb + jn * 16 + col;
        half8 bf_n = (quad < 2) ? bkv[(size_t)(p8 + n) * 2 + quad] : zf;
        float hbs_n = hbp[n];

        float tb = INF;
#pragma unroll
        for (int i = 0; i < 4; ++i) {
            float4v c;
            c.x = haT[i].x + hbs;
            c.y = haT[i].y + hbs;
            c.z = haT[i].z + hbs;
            c.w = haT[i].w + hbs;
            c = __builtin_amdgcn_mfma_f32_16x16x32_f16(af[i], bf, c, 0, 0, 0);
            minA[i].x = fminf(minA[i].x, c.x);
            minA[i].y = fminf(minA[i].y, c.y);
            minA[i].z = fminf(minA[i].z, c.z);
            minA[i].w = fminf(minA[i].w, c.w);
            tb = fminf(tb, fminf(fminf(c.x, c.y), fminf(c.z, c.w)));
        }
        // col-min for this j-tile: reduce across quads (rows), col fixed.
        tb = fminf(tb, __shfl_xor(tb, 16));
        tb = fminf(tb, __shfl_xor(tb, 32));
        if (lane < 16) sMB[w * 512 + j * 16 + col] = tb;

        bf = bf_n;
        hbs = hbs_n;
    }

    // minA: reduce across the 16 col-lanes of each quad; write per-wave rows.
#pragma unroll
    for (int i = 0; i < 4; ++i) {
        float v0 = minA[i].x, v1 = minA[i].y, v2 = minA[i].z, v3 = minA[i].w;
#pragma unroll
        for (int s = 1; s < 16; s <<= 1) {
            v0 = fminf(v0, __shfl_xor(v0, s));
            v1 = fminf(v1, __shfl_xor(v1, s));
            v2 = fminf(v2, __shfl_xor(v2, s));
            v3 = fminf(v3, __shfl_xor(v3, s));
        }
        if (col == 0) {
            float4v pack = {v0, v1, v2, v3};
            *(float4v*)&sMA[w * 64 + i * 16 + quad * 4] = pack;
        }
    }
    __syncthreads();

    // Coalesced global merges: 256 consecutive rows, 512 consecutive cols.
    atomicMin((unsigned int*)&mins[p8 + mb + tid], __float_as_uint(sMA[tid]));
#pragma unroll
    for (int c = tid; c < 512; c += 256) {
        float v = fminf(fminf(sMB[c], sMB[512 + c]),
                        fminf(sMB[1024 + c], sMB[1536 + c]));
        atomicMin((unsigned int*)&mins[NP * NM + p8 + nb + c],
                  __float_as_uint(v));
    }
}

__global__ __launch_bounds__(256) void finalize_kernel(
    const float* __restrict__ ws, const float* __restrict__ w,
    float* __restrict__ out) {
    // mins hold s = 0.5*d^2 -> d = sqrt(max(2s, 0)).
    const float* vals = ws + MINS_OFF;
    int i = blockIdx.x * 256 + threadIdx.x;  // [0, 32768)
    int tid = threadIdx.x;

    float wl[4] = {w[0], w[1], w[2], w[3]};

    int i2 = i + 32768;
    float acc = wl[(i >> 13) & 3] * sqrtf(fmaxf(2.0f * vals[i], 0.0f)) +
                wl[(i2 >> 13) & 3] * sqrtf(fmaxf(2.0f * vals[i2], 0.0f));

#pragma unroll
    for (int off = 32; off > 0; off >>= 1) acc += __shfl_down(acc, off, 64);

    __shared__ float wsum[4];
    if ((tid & 63) == 0) wsum[tid >> 6] = acc;
    __syncthreads();
    if (tid == 0) {
        float blocksum = (wsum[0] + wsum[1] + wsum[2] + wsum[3]) * (1.0f / 8192.0f);
        atomicAdd(out, blocksum);
    }
}

extern "C" void kernel_launch(void* const* d_in, const int* in_sizes, int n_in,
                              void* d_out, int out_size, void* d_ws, size_t ws_size,
                              hipStream_t stream) {
    const float* cam = (const float*)d_in[0];   // (P, N, 3)
    const float* cad = (const float*)d_in[1];   // (P, M, 3)
    const float* w = (const float*)d_in[2];     // (P,)
    const float* quat = (const float*)d_in[3];  // (P, 4)
    const float* tra = (const float*)d_in[4];   // (P, 3, 1)
    float* out = (float*)d_out;
    float* ws = (float*)d_ws;

    prep_kernel<<<256, 256, 0, stream>>>(cam, cad, quat, tra, ws, out);

    dim3 grid(NM / 256, NN / 512, NP);
    chamfer_mfma<<<grid, 256, 0, stream>>>(ws, ws + MINS_OFF);

    finalize_kernel<<<128, 256, 0, stream>>>(ws, w, out);
}